// Round 5
// baseline (87.312 us; speedup 1.0000x reference)
//
#include <hip/hip_runtime.h>
#include <hip/hip_bf16.h>

#define N_ROWS 262144
#define DIM    64
#define KCB    512

#define BLOCKS  512
#define THREADS 512          // 8 waves; wave pair {p,p+4} shares 128 rows

typedef __bf16 bf16x8 __attribute__((ext_vector_type(8)));
typedef float  f32x4  __attribute__((ext_vector_type(4)));

__device__ inline float dot4(float4 a) {
    return a.x * a.x + a.y * a.y + a.z * a.z + a.w * a.w;
}
__device__ inline unsigned umin2(unsigned a, unsigned b) { return a < b ? a : b; }

// ---- kernel 1: stage+wnorm, split-K argmin, combine, gather-store, loss ----
__global__ __launch_bounds__(THREADS, 4) void vq_main(
    const float* __restrict__ x, const float* __restrict__ cb,
    float* __restrict__ out, float* __restrict__ partials)
{
    __shared__ bf16x8   cb_sh[KCB * 8];    // 64 KiB, negated bf16, XOR-swizzled
    __shared__ f32x4    wn_sh4[KCB / 4];   // 2 KiB: wn[k] = 1 + 0.5||w_k||^2
    __shared__ unsigned cmb[8][128];       // 4 KiB: per-wave packed mins
    __shared__ float    red_sh[8];

    const int tid    = threadIdx.x;
    const int lane   = tid & 63;
    const int wave   = tid >> 6;           // 0..7
    const int lane15 = lane & 15;
    const int half   = lane >> 4;          // 0..3
    const int pair   = wave & 3;           // row group 0..3
    const int khalf  = wave >> 2;          // codebook half 0..1

    // ---- stage NEGATED codebook f32 -> bf16 into LDS; fold in wn compute ----
    #pragma unroll
    for (int it = 0; it < (KCB * 8) / THREADS; ++it) {
        const int fg = tid + it * THREADS;
        const int row = fg >> 3, g = fg & 7;
        const float* src = cb + row * DIM + g * 8;
        float4 f0 = *(const float4*)src;
        float4 f1 = *(const float4*)(src + 4);
        float sq = dot4(f0) + dot4(f1);
        sq += __shfl_xor(sq, 1);
        sq += __shfl_xor(sq, 2);
        sq += __shfl_xor(sq, 4);
        bf16x8 v;
        v[0] = (__bf16)(-f0.x); v[1] = (__bf16)(-f0.y); v[2] = (__bf16)(-f0.z); v[3] = (__bf16)(-f0.w);
        v[4] = (__bf16)(-f1.x); v[5] = (__bf16)(-f1.y); v[6] = (__bf16)(-f1.z); v[7] = (__bf16)(-f1.w);
        cb_sh[row * 8 + (g ^ (row & 7))] = v;
        if (g == 0) ((float*)wn_sh4)[row] = 1.0f + 0.5f * sq;
    }
    __syncthreads();

    const int swz_lo = half ^ (lane & 7);
    const int swz_hi = (4 + half) ^ (lane & 7);
    const unsigned kbase = ((unsigned)khalf << 8) | (unsigned)(half * 4);
    const int rowbase = blockIdx.x * 512 + pair * 128;

    unsigned u[8];
    float    xn[8];

    // ---- two phases of 4 columns (64 rows each); 16 t-iters per phase ------
    #pragma unroll
    for (int ph = 0; ph < 2; ++ph) {
        bf16x8 blo[4], bhi[4];
        #pragma unroll
        for (int c = 0; c < 4; ++c) {
            const int col = ph * 4 + c;
            const float* xr = x + (size_t)(rowbase + col * 16 + lane15) * DIM + half * 8;
            float4 f0 = *(const float4*)xr;
            float4 f1 = *(const float4*)(xr + 4);
            float4 f2 = *(const float4*)(xr + 32);
            float4 f3 = *(const float4*)(xr + 36);
            xn[col] = dot4(f0) + dot4(f1) + dot4(f2) + dot4(f3);
            bf16x8 lo, hi;
            lo[0] = (__bf16)f0.x; lo[1] = (__bf16)f0.y; lo[2] = (__bf16)f0.z; lo[3] = (__bf16)f0.w;
            lo[4] = (__bf16)f1.x; lo[5] = (__bf16)f1.y; lo[6] = (__bf16)f1.z; lo[7] = (__bf16)f1.w;
            hi[0] = (__bf16)f2.x; hi[1] = (__bf16)f2.y; hi[2] = (__bf16)f2.z; hi[3] = (__bf16)f2.w;
            hi[4] = (__bf16)f3.x; hi[5] = (__bf16)f3.y; hi[6] = (__bf16)f3.z; hi[7] = (__bf16)f3.w;
            blo[c] = lo; bhi[c] = hi;
        }
        u[ph * 4 + 0] = 0xFFFFFFFFu; u[ph * 4 + 1] = 0xFFFFFFFFu;
        u[ph * 4 + 2] = 0xFFFFFFFFu; u[ph * 4 + 3] = 0xFFFFFFFFu;

        #pragma unroll 4
        for (int t = 0; t < 16; ++t) {
            const int arow = khalf * 256 + t * 16 + lane15;
            bf16x8 alo = cb_sh[arow * 8 + swz_lo];
            bf16x8 ahi = cb_sh[arow * 8 + swz_hi];
            f32x4  wnv = wn_sh4[khalf * 64 + t * 4 + half];
            const unsigned kb = kbase | (unsigned)(t * 16);
            #pragma unroll
            for (int c = 0; c < 4; ++c) {
                f32x4 acc = wnv;     // C-init = wn; A = -w -> acc = wn - x.w
                acc = __builtin_amdgcn_mfma_f32_16x16x32_bf16(alo, blo[c], acc, 0, 0, 0);
                acc = __builtin_amdgcn_mfma_f32_16x16x32_bf16(ahi, bhi[c], acc, 0, 0, 0);
                unsigned p0 = (__float_as_uint(acc[0]) & 0xFFFFFE00u) | kb;
                unsigned p1 = (__float_as_uint(acc[1]) & 0xFFFFFE00u) | (kb | 1u);
                unsigned p2 = (__float_as_uint(acc[2]) & 0xFFFFFE00u) | (kb | 2u);
                unsigned p3 = (__float_as_uint(acc[3]) & 0xFFFFFE00u) | (kb | 3u);
                unsigned m = umin2(umin2(p0, p1), umin2(p2, p3));
                u[ph * 4 + c] = umin2(u[ph * 4 + c], m);
            }
        }
    }

    // ---- reduce across halves; exchange with partner wave; global min ------
    unsigned fin[8];
    #pragma unroll
    for (int c = 0; c < 8; ++c) {
        unsigned v = u[c];
        v = umin2(v, (unsigned)__shfl_xor((int)v, 16));
        v = umin2(v, (unsigned)__shfl_xor((int)v, 32));
        fin[c] = v;
    }
    if (lane < 16) {
        #pragma unroll
        for (int c = 0; c < 8; ++c) cmb[wave][c * 16 + lane] = fin[c];
    }
    __syncthreads();
    #pragma unroll
    for (int c = 0; c < 8; ++c)
        fin[c] = umin2(fin[c], cmb[wave ^ 4][c * 16 + lane15]);

    // ---- loss from winner score (khalf==0 waves only, avoid double count) --
    // per lane: 0.25 * ||x-q||^2 ; the 4 half-lanes duplicate each row, so the
    // wave-sum is exactly 1.0 * sum_rows ||x-q||^2 (0.25 is the dedup factor).
    float lossAcc = 0.f;
    #pragma unroll
    for (int c = 0; c < 8; ++c) {
        float xnf = xn[c];
        xnf += __shfl_xor(xnf, 16);
        xnf += __shfl_xor(xnf, 32);
        float sstar = __uint_as_float(fin[c] & 0xFFFFFE00u); // 1+0.5||q||^2-x.q
        lossAcc += 0.25f * (xnf + 2.f * (sstar - 1.f));      // 0.25*||x-q||^2
    }
    if (khalf) lossAcc = 0.f;

    // ---- coalesced gather + store: wave stores its 64 rows, 1KB/instr ------
    float* outw = out + (size_t)(rowbase + khalf * 64) * DIM;
    #pragma unroll
    for (int j = 0; j < 16; ++j) {
        const int cl = j >> 2;                       // local col 0..3
        unsigned fv = khalf ? fin[4 + cl] : fin[cl]; // static indices only
        const int srcl = (j * 4 + half) & 15;
        int bk = __shfl((int)(fv & 511u), srcl);
        float4 q = *(const float4*)(cb + (size_t)bk * DIM + (lane & 15) * 4);
        *(float4*)(outw + j * 256 + lane * 4) = q;
    }

    // ---- loss partial ----
    #pragma unroll
    for (int off = 1; off < 64; off <<= 1) lossAcc += __shfl_xor(lossAcc, off);
    if (lane == 0) red_sh[wave] = lossAcc;
    __syncthreads();
    if (tid == 0) {
        float s = 0.f;
        #pragma unroll
        for (int w = 0; w < 8; ++w) s += red_sh[w];
        partials[blockIdx.x] = s;
    }
}

// ---- kernel 2: final loss reduction ----------------------------------------
__global__ void vq_finalize(const float* __restrict__ partials,
                            float* __restrict__ out_loss) {
    __shared__ float sh[256];
    int t = threadIdx.x;
    sh[t] = partials[t] + partials[t + 256];
    __syncthreads();
    #pragma unroll
    for (int s = 128; s > 0; s >>= 1) {
        if (t < s) sh[t] += sh[t + s];
        __syncthreads();
    }
    // partials = sum_rows ||x-q||^2 ; vq_loss = 1.25 * sum / (N*D)
    if (t == 0) out_loss[0] = sh[0] * (1.25f / (float)(N_ROWS * DIM));
}

extern "C" void kernel_launch(void* const* d_in, const int* in_sizes, int n_in,
                              void* d_out, int out_size, void* d_ws, size_t ws_size,
                              hipStream_t stream) {
    const float* x  = (const float*)d_in[0];
    const float* cb = (const float*)d_in[1];
    float* out      = (float*)d_out;
    float* partials = (float*)d_ws;        // BLOCKS floats

    hipLaunchKernelGGL(vq_main, dim3(BLOCKS), dim3(THREADS), 0, stream,
                       x, cb, out, partials);
    hipLaunchKernelGGL(vq_finalize, dim3(1), dim3(256), 0, stream,
                       partials, out + (size_t)N_ROWS * DIM);
}

// Round 6
// 39.957 us; speedup vs baseline: 2.1852x; 2.1852x over previous
//
#include <hip/hip_runtime.h>
#include <hip/hip_bf16.h>

#define N_ROWS 262144
#define DIM    64
#define KCB    512

#define BLOCKS  512
#define THREADS 512          // 8 waves; each wave: 64 rows = 2 chunks x 32

typedef __bf16 bf16x8 __attribute__((ext_vector_type(8)));
typedef float  f32x4  __attribute__((ext_vector_type(4)));

__device__ inline float dot4(float4 a) {
    return a.x * a.x + a.y * a.y + a.z * a.z + a.w * a.w;
}
__device__ inline unsigned umin2(unsigned a, unsigned b) { return a < b ? a : b; }

// convert one column's 4 raw float4 -> bf16 A/B fragments + partial ||x||^2
__device__ inline void conv_col(float4 f0, float4 f1, float4 f2, float4 f3,
                                bf16x8& lo, bf16x8& hi, float& xn) {
    xn = dot4(f0) + dot4(f1) + dot4(f2) + dot4(f3);
    lo[0] = (__bf16)f0.x; lo[1] = (__bf16)f0.y; lo[2] = (__bf16)f0.z; lo[3] = (__bf16)f0.w;
    lo[4] = (__bf16)f1.x; lo[5] = (__bf16)f1.y; lo[6] = (__bf16)f1.z; lo[7] = (__bf16)f1.w;
    hi[0] = (__bf16)f2.x; hi[1] = (__bf16)f2.y; hi[2] = (__bf16)f2.z; hi[3] = (__bf16)f2.w;
    hi[4] = (__bf16)f3.x; hi[5] = (__bf16)f3.y; hi[6] = (__bf16)f3.z; hi[7] = (__bf16)f3.w;
}

// ---- kernel 1: stage+wnorm, pipelined 2-chunk argmin, gather-store, loss ---
__global__ __launch_bounds__(THREADS, 2) void vq_main(
    const float* __restrict__ x, const float* __restrict__ cb,
    float* __restrict__ out, float* __restrict__ partials)
{
    __shared__ bf16x8 cb_sh[KCB * 8];      // 64 KiB, negated bf16, XOR-swizzled
    __shared__ f32x4  wn_sh4[KCB / 4];     // 2 KiB: wn[k] = 1 + 0.5||w_k||^2
    __shared__ float  red_sh[8];

    const int tid    = threadIdx.x;
    const int lane   = tid & 63;
    const int wave   = tid >> 6;           // 0..7
    const int lane15 = lane & 15;
    const int half   = lane >> 4;          // 0..3

    const int wrow = blockIdx.x * 512 + wave * 64;
    // chunk 0 = rows [wrow, wrow+32), chunk 1 = [wrow+32, wrow+64)
    const float* xc0 = x + (size_t)(wrow + lane15) * DIM + half * 8;        // col0
    const float* xc1 = x + (size_t)(wrow + 16 + lane15) * DIM + half * 8;   // col1

    // ---- issue chunk0 x-loads (in flight during staging) -------------------
    float4 p00 = *(const float4*)xc0,        p01 = *(const float4*)(xc0 + 4);
    float4 p02 = *(const float4*)(xc0 + 32), p03 = *(const float4*)(xc0 + 36);
    float4 p10 = *(const float4*)xc1,        p11 = *(const float4*)(xc1 + 4);
    float4 p12 = *(const float4*)(xc1 + 32), p13 = *(const float4*)(xc1 + 36);

    // ---- stage NEGATED codebook f32 -> bf16 into LDS; fold in wn -----------
    #pragma unroll
    for (int it = 0; it < (KCB * 8) / THREADS; ++it) {
        const int fg = tid + it * THREADS;
        const int row = fg >> 3, g = fg & 7;
        const float* src = cb + row * DIM + g * 8;
        float4 f0 = *(const float4*)src;
        float4 f1 = *(const float4*)(src + 4);
        float sq = dot4(f0) + dot4(f1);
        sq += __shfl_xor(sq, 1);
        sq += __shfl_xor(sq, 2);
        sq += __shfl_xor(sq, 4);
        bf16x8 v;
        v[0] = (__bf16)(-f0.x); v[1] = (__bf16)(-f0.y); v[2] = (__bf16)(-f0.z); v[3] = (__bf16)(-f0.w);
        v[4] = (__bf16)(-f1.x); v[5] = (__bf16)(-f1.y); v[6] = (__bf16)(-f1.z); v[7] = (__bf16)(-f1.w);
        cb_sh[row * 8 + (g ^ (row & 7))] = v;
        if (g == 0) ((float*)wn_sh4)[row] = 1.0f + 0.5f * sq;
    }

    // ---- convert chunk0 while the barrier drains ---------------------------
    bf16x8 b0lo, b0hi, b1lo, b1hi;
    float  xn0, xn1;
    conv_col(p00, p01, p02, p03, b0lo, b0hi, xn0);
    conv_col(p10, p11, p12, p13, b1lo, b1hi, xn1);
    __syncthreads();

    // ---- issue chunk1 x-loads (in flight during chunk0 score loop) --------
    float4 q00 = *(const float4*)(xc0 + 2048),  q01 = *(const float4*)(xc0 + 2052);
    float4 q02 = *(const float4*)(xc0 + 2080),  q03 = *(const float4*)(xc0 + 2084);
    float4 q10 = *(const float4*)(xc1 + 2048),  q11 = *(const float4*)(xc1 + 2052);
    float4 q12 = *(const float4*)(xc1 + 2080),  q13 = *(const float4*)(xc1 + 2084);

    const int swz_lo = half ^ (lane & 7);
    const int swz_hi = (4 + half) ^ (lane & 7);
    const unsigned hb = (unsigned)(half * 4);
    float lossAcc = 0.f;

    #pragma unroll
    for (int ch = 0; ch < 2; ++ch) {
        if (ch == 1) {   // convert prefetched chunk1 (loads complete by now)
            conv_col(q00, q01, q02, q03, b0lo, b0hi, xn0);
            conv_col(q10, q11, q12, q13, b1lo, b1hi, xn1);
        }
        unsigned u0 = 0xFFFFFFFFu, u1 = 0xFFFFFFFFu;

        #pragma unroll 8
        for (int t = 0; t < 32; ++t) {
            const int arow = t * 16 + lane15;
            bf16x8 alo = cb_sh[arow * 8 + swz_lo];
            bf16x8 ahi = cb_sh[arow * 8 + swz_hi];
            f32x4  wnv = wn_sh4[t * 4 + half];
            const unsigned kb = (unsigned)(t * 16) | hb;

            f32x4 acc = wnv;      // C-init = wn; A = -w -> acc = wn - x.w
            acc = __builtin_amdgcn_mfma_f32_16x16x32_bf16(alo, b0lo, acc, 0, 0, 0);
            acc = __builtin_amdgcn_mfma_f32_16x16x32_bf16(ahi, b0hi, acc, 0, 0, 0);
            unsigned p0 = (__float_as_uint(acc[0]) & 0xFFFFFE00u) | kb;
            unsigned p1 = (__float_as_uint(acc[1]) & 0xFFFFFE00u) | (kb | 1u);
            unsigned p2 = (__float_as_uint(acc[2]) & 0xFFFFFE00u) | (kb | 2u);
            unsigned p3 = (__float_as_uint(acc[3]) & 0xFFFFFE00u) | (kb | 3u);
            u0 = umin2(u0, umin2(umin2(p0, p1), umin2(p2, p3)));

            f32x4 acd = wnv;
            acd = __builtin_amdgcn_mfma_f32_16x16x32_bf16(alo, b1lo, acd, 0, 0, 0);
            acd = __builtin_amdgcn_mfma_f32_16x16x32_bf16(ahi, b1hi, acd, 0, 0, 0);
            unsigned r0 = (__float_as_uint(acd[0]) & 0xFFFFFE00u) | kb;
            unsigned r1 = (__float_as_uint(acd[1]) & 0xFFFFFE00u) | (kb | 1u);
            unsigned r2 = (__float_as_uint(acd[2]) & 0xFFFFFE00u) | (kb | 2u);
            unsigned r3 = (__float_as_uint(acd[3]) & 0xFFFFFE00u) | (kb | 3u);
            u1 = umin2(u1, umin2(umin2(r0, r1), umin2(r2, r3)));
        }

        // ---- reduce across 4 halves (same lane15 = same x-row) -------------
        unsigned f0 = u0;
        f0 = umin2(f0, (unsigned)__shfl_xor((int)f0, 16));
        f0 = umin2(f0, (unsigned)__shfl_xor((int)f0, 32));
        unsigned f1 = u1;
        f1 = umin2(f1, (unsigned)__shfl_xor((int)f1, 16));
        f1 = umin2(f1, (unsigned)__shfl_xor((int)f1, 32));

        float xs0 = xn0;
        xs0 += __shfl_xor(xs0, 16); xs0 += __shfl_xor(xs0, 32);
        float xs1 = xn1;
        xs1 += __shfl_xor(xs1, 16); xs1 += __shfl_xor(xs1, 32);

        // per lane 0.25*||x-q||^2; 4 half-lanes duplicate each row -> wave sum
        // = 1.0 * sum_rows ||x-q||^2  (R2-proven)
        float s0 = __uint_as_float(f0 & 0xFFFFFE00u);   // 1+0.5||q||^2-x.q
        float s1 = __uint_as_float(f1 & 0xFFFFFE00u);
        lossAcc += 0.25f * (xs0 + 2.f * (s0 - 1.f));
        lossAcc += 0.25f * (xs1 + 2.f * (s1 - 1.f));

        const int bk0 = (int)(f0 & 511u);
        const int bk1 = (int)(f1 & 511u);

        // ---- coalesced gather + store: instr j writes 1KB contiguous -------
        float* outw = out + (size_t)(wrow + ch * 32) * DIM;
        #pragma unroll
        for (int j = 0; j < 8; ++j) {
            const int srcl = (j * 4 + half) & 15;
            int bk = __shfl((j >> 2) ? bk1 : bk0, srcl);
            float4 qv = *(const float4*)(cb + (size_t)bk * DIM + (lane & 15) * 4);
            *(float4*)(outw + j * 256 + lane * 4) = qv;
        }
    }

    // ---- loss partial ------------------------------------------------------
    #pragma unroll
    for (int off = 1; off < 64; off <<= 1) lossAcc += __shfl_xor(lossAcc, off);
    if (lane == 0) red_sh[wave] = lossAcc;
    __syncthreads();
    if (tid == 0) {
        float s = 0.f;
        #pragma unroll
        for (int w = 0; w < 8; ++w) s += red_sh[w];
        partials[blockIdx.x] = s;
    }
}

// ---- kernel 2: final loss reduction ----------------------------------------
__global__ void vq_finalize(const float* __restrict__ partials,
                            float* __restrict__ out_loss) {
    __shared__ float sh[256];
    int t = threadIdx.x;
    sh[t] = partials[t] + partials[t + 256];
    __syncthreads();
    #pragma unroll
    for (int s = 128; s > 0; s >>= 1) {
        if (t < s) sh[t] += sh[t + s];
        __syncthreads();
    }
    // partials = sum_rows ||x-q||^2 ; vq_loss = 1.25 * sum / (N*D)
    if (t == 0) out_loss[0] = sh[0] * (1.25f / (float)(N_ROWS * DIM));
}

extern "C" void kernel_launch(void* const* d_in, const int* in_sizes, int n_in,
                              void* d_out, int out_size, void* d_ws, size_t ws_size,
                              hipStream_t stream) {
    const float* x  = (const float*)d_in[0];
    const float* cb = (const float*)d_in[1];
    float* out      = (float*)d_out;
    float* partials = (float*)d_ws;        // BLOCKS floats

    hipLaunchKernelGGL(vq_main, dim3(BLOCKS), dim3(THREADS), 0, stream,
                       x, cb, out, partials);
    hipLaunchKernelGGL(vq_finalize, dim3(1), dim3(256), 0, stream,
                       partials, out + (size_t)N_ROWS * DIM);
}